// Round 11
// baseline (5934.144 us; speedup 1.0000x reference)
//
#include <hip/hip_runtime.h>
#include <math.h>
#include <limits.h>

#define NB 1024   // batch
#define NF 2048   // features
#define NV 10000  // vocab
#define NE 256    // embed
#define NH 512    // hidden
#define ND 3      // distractors
#define NT 20     // max sentence length
#define NBX ((NV + 127) / 128)   // 79 logits col-blocks
#define NCANDW (NBX * 2)         // 158 candidate slots per row

typedef __bf16 bf16x8 __attribute__((ext_vector_type(8)));
typedef float  f32x4  __attribute__((ext_vector_type(4)));

__device__ __forceinline__ float sigf(float x) { return 1.0f / (1.0f + expf(-x)); }
__device__ __forceinline__ bool better(float v, int i, float w, int j) {
    return (v > w) || (v == w && i < j);
}
// merge sorted pair (w1>=w2) into running top-2 (v1,i1,v2,i2)
__device__ __forceinline__ void merge2(float& v1, int& i1, float& v2, int& i2,
                                       float w1, int j1, float w2, int j2) {
    if (better(w1, j1, v1, i1)) {
        if (better(v1, i1, w2, j2)) { v2 = v1; i2 = i1; }
        else                        { v2 = w2; i2 = j2; }
        v1 = w1; i1 = j1;
    } else if (better(w1, j1, v2, i2)) { v2 = w1; i2 = j1; }
}

// ---------------- fp32 GEMM: C = A[M,K] @ B[N,K]^T (+bias) (+accum) ----------
// tile 64(M)x128(N), BK=16, 512 threads, 4x4/thread. Ascending-k fmaf chain ==
// validated baseline -> sender h BIT-IDENTICAL. GATHER: A row r = A[gidx[r]*K].
template<int ACCUM, int BIAS, int ZMODE, int GATHER>
__global__ __launch_bounds__(512)
void gemm512(const float* __restrict__ A, const float* __restrict__ A2,
             const int* __restrict__ gidx,
             const float* __restrict__ Bm, const float* __restrict__ bias,
             float* __restrict__ C, int M, int N, int K)
{
    __shared__ float As[16][68];
    __shared__ float Bs[16][132];
    const int tid = threadIdx.x;
    const int bn = blockIdx.x << 7;
    const int bm = blockIdx.y << 6;

    const float* Ause = A;
    if (ZMODE) {
        if (blockIdx.z > 0) Ause = A2 + (size_t)(blockIdx.z - 1) * M * K;
        C += (size_t)blockIdx.z * M * N;
    }

    const int abr = tid & 63;
    const int abk = ((tid >> 6) & 3) << 2;
    const int bbr = tid & 127;
    const int bbk = (tid >> 7) << 2;
    const int tx = tid & 31, ty = tid >> 5;
    const int m0 = ty << 2, n0 = tx << 2;

    const float* Arow = nullptr;
    if (tid < 256) {
        int r = bm + abr;
        Arow = GATHER ? (A + (size_t)gidx[r] * K) : (Ause + (size_t)r * K);
    }
    const float* Brow = Bm + (size_t)(bn + bbr) * K;

    float acc[4][4];
    #pragma unroll
    for (int i = 0; i < 4; ++i)
        #pragma unroll
        for (int j = 0; j < 4; ++j) acc[i][j] = 0.f;

    for (int k0 = 0; k0 < K; k0 += 16) {
        if (tid < 256) {
            float4 av = *(const float4*)(Arow + k0 + abk);
            As[abk + 0][abr] = av.x; As[abk + 1][abr] = av.y;
            As[abk + 2][abr] = av.z; As[abk + 3][abr] = av.w;
        }
        float4 bv = *(const float4*)(Brow + k0 + bbk);
        Bs[bbk + 0][bbr] = bv.x; Bs[bbk + 1][bbr] = bv.y;
        Bs[bbk + 2][bbr] = bv.z; Bs[bbk + 3][bbr] = bv.w;
        __syncthreads();
        #pragma unroll
        for (int k = 0; k < 16; ++k) {
            float4 xa = *(const float4*)&As[k][m0];
            float4 xb = *(const float4*)&Bs[k][n0];
            float ar[4] = {xa.x, xa.y, xa.z, xa.w};
            float br[4] = {xb.x, xb.y, xb.z, xb.w};
            #pragma unroll
            for (int i = 0; i < 4; ++i)
                #pragma unroll
                for (int j = 0; j < 4; ++j)
                    acc[i][j] = fmaf(ar[i], br[j], acc[i][j]);
        }
        __syncthreads();
    }
    #pragma unroll
    for (int i = 0; i < 4; ++i) {
        int row = bm + m0 + i;
        #pragma unroll
        for (int j = 0; j < 4; ++j) {
            int col = bn + n0 + j;
            float v = acc[i][j];
            if (BIAS) v += bias[col];
            float* p = C + (size_t)row * N + col;
            if (ACCUM) v += *p;
            *p = v;
        }
    }
}

// ---------------- h0: 32(M)x128(N) tile fp32 (2x block count for M=1024,N=512)
// Same ascending-k fmaf chain per output element -> bit-identical h0.
__global__ __launch_bounds__(256)
void h0_gemm(const float* __restrict__ A, const float* __restrict__ Bm,
             const float* __restrict__ bias, float* __restrict__ C,
             int M, int N, int K)
{
    __shared__ float As[16][36];
    __shared__ float Bs[16][132];
    const int tid = threadIdx.x;
    const int bn = blockIdx.x << 7;
    const int bm = blockIdx.y << 5;

    const int abr = tid & 31;
    const int abk = ((tid >> 5) & 3) << 2;   // threads 0..127 stage A
    const int bbr = tid & 127;
    const int bbk = (tid >> 7) << 3;         // 0 or 8, two float4 each
    const int tx = tid & 31, ty = tid >> 5;
    const int m0 = ty << 2, n0 = tx << 2;

    const float* Arow = A + (size_t)(bm + abr) * K;
    const float* Brow = Bm + (size_t)(bn + bbr) * K;

    float acc[4][4];
    #pragma unroll
    for (int i = 0; i < 4; ++i)
        #pragma unroll
        for (int j = 0; j < 4; ++j) acc[i][j] = 0.f;

    for (int k0 = 0; k0 < K; k0 += 16) {
        if (tid < 128) {
            float4 av = *(const float4*)(Arow + k0 + abk);
            As[abk + 0][abr] = av.x; As[abk + 1][abr] = av.y;
            As[abk + 2][abr] = av.z; As[abk + 3][abr] = av.w;
        }
        float4 b0 = *(const float4*)(Brow + k0 + bbk);
        float4 b1 = *(const float4*)(Brow + k0 + bbk + 4);
        Bs[bbk + 0][bbr] = b0.x; Bs[bbk + 1][bbr] = b0.y;
        Bs[bbk + 2][bbr] = b0.z; Bs[bbk + 3][bbr] = b0.w;
        Bs[bbk + 4][bbr] = b1.x; Bs[bbk + 5][bbr] = b1.y;
        Bs[bbk + 6][bbr] = b1.z; Bs[bbk + 7][bbr] = b1.w;
        __syncthreads();
        #pragma unroll
        for (int k = 0; k < 16; ++k) {
            float4 xa = *(const float4*)&As[k][m0];
            float4 xb = *(const float4*)&Bs[k][n0];
            float ar[4] = {xa.x, xa.y, xa.z, xa.w};
            float br[4] = {xb.x, xb.y, xb.z, xb.w};
            #pragma unroll
            for (int i = 0; i < 4; ++i)
                #pragma unroll
                for (int j = 0; j < 4; ++j)
                    acc[i][j] = fmaf(ar[i], br[j], acc[i][j]);
        }
        __syncthreads();
    }
    #pragma unroll
    for (int i = 0; i < 4; ++i) {
        int row = bm + m0 + i;
        #pragma unroll
        for (int j = 0; j < 4; ++j) {
            int col = bn + n0 + j;
            C[(size_t)row * N + col] = acc[i][j] + bias[col];
        }
    }
}

// ---------------- split fp32 -> hi/lo bf16 planes ----------------------------
__global__ void split_k(const float* __restrict__ x, __bf16* __restrict__ hi,
                        __bf16* __restrict__ lo, int n)
{
    int i = blockIdx.x * 256 + threadIdx.x;
    if (i < n) {
        float v = x[i];
        __bf16 h = (__bf16)v;
        hi[i] = h;
        lo[i] = (__bf16)(v - (float)h);
    }
}

// ---------------- logits MFMA + fused per-block row top-2 --------------------
// C[NB,NV] = h @ W^T + bias via split-bf16 (3 MFMA products). Tile 128x128,
// BK=32, 4 waves 2x2. Epilogue: per-row top-2 over the block's 128 cols via
// 16-lane shuffle butterfly -> cand[row][bx*2+wn]. Values bit-equal to C.
__global__ __launch_bounds__(256)
void logits_mfma(const __bf16* __restrict__ Ahi, const __bf16* __restrict__ Alo,
                 const __bf16* __restrict__ Bhi, const __bf16* __restrict__ Blo,
                 const float* __restrict__ bias, float* __restrict__ C,
                 float4* __restrict__ cand)
{
    __shared__ __align__(16) char sm[32768];
    __bf16* sAh = (__bf16*)sm;
    __bf16* sAl = (__bf16*)(sm + 8192);
    __bf16* sBh = (__bf16*)(sm + 16384);
    __bf16* sBl = (__bf16*)(sm + 24576);

    const int tid = threadIdx.x;
    const int lane = tid & 63, w = tid >> 6;
    const int wm = w >> 1, wn = w & 1;
    const int bm = blockIdx.y << 7, bn = blockIdx.x << 7;

    size_t ga[2], gb[2];
    #pragma unroll
    for (int j = 0; j < 2; ++j) {
        int s = tid + j * 256;
        int mf = s >> 6, g = (s >> 4) & 3, row = s & 15;
        ga[j] = (size_t)(bm + mf * 16 + row) * NH + g * 8;
        int n = bn + mf * 16 + row;
        if (n >= NV) n = 0;
        gb[j] = (size_t)n * NH + g * 8;
    }

    f32x4 acc[4][4];
    #pragma unroll
    for (int i = 0; i < 4; ++i)
        #pragma unroll
        for (int j = 0; j < 4; ++j) acc[i][j] = (f32x4){0.f, 0.f, 0.f, 0.f};

    for (int k0 = 0; k0 < NH; k0 += 32) {
        uint4 vah0 = *(const uint4*)(Ahi + ga[0] + k0);
        uint4 vah1 = *(const uint4*)(Ahi + ga[1] + k0);
        uint4 val0 = *(const uint4*)(Alo + ga[0] + k0);
        uint4 val1 = *(const uint4*)(Alo + ga[1] + k0);
        uint4 vbh0 = *(const uint4*)(Bhi + gb[0] + k0);
        uint4 vbh1 = *(const uint4*)(Bhi + gb[1] + k0);
        uint4 vbl0 = *(const uint4*)(Blo + gb[0] + k0);
        uint4 vbl1 = *(const uint4*)(Blo + gb[1] + k0);
        *(uint4*)(sAh + (size_t)tid * 8)         = vah0;
        *(uint4*)(sAh + (size_t)(tid + 256) * 8) = vah1;
        *(uint4*)(sAl + (size_t)tid * 8)         = val0;
        *(uint4*)(sAl + (size_t)(tid + 256) * 8) = val1;
        *(uint4*)(sBh + (size_t)tid * 8)         = vbh0;
        *(uint4*)(sBh + (size_t)(tid + 256) * 8) = vbh1;
        *(uint4*)(sBl + (size_t)tid * 8)         = vbl0;
        *(uint4*)(sBl + (size_t)(tid + 256) * 8) = vbl1;
        __syncthreads();

        bf16x8 ah[4], al[4];
        #pragma unroll
        for (int f = 0; f < 4; ++f) {
            int base = ((wm * 4 + f) * 64 + lane) * 8;
            ah[f] = *(const bf16x8*)(sAh + base);
            al[f] = *(const bf16x8*)(sAl + base);
        }
        #pragma unroll
        for (int fn = 0; fn < 4; ++fn) {
            int base = ((wn * 4 + fn) * 64 + lane) * 8;
            bf16x8 bh = *(const bf16x8*)(sBh + base);
            bf16x8 bl = *(const bf16x8*)(sBl + base);
            #pragma unroll
            for (int fm = 0; fm < 4; ++fm)
                acc[fm][fn] = __builtin_amdgcn_mfma_f32_16x16x32_bf16(ah[fm], bh, acc[fm][fn], 0, 0, 0);
            #pragma unroll
            for (int fm = 0; fm < 4; ++fm)
                acc[fm][fn] = __builtin_amdgcn_mfma_f32_16x16x32_bf16(ah[fm], bl, acc[fm][fn], 0, 0, 0);
            #pragma unroll
            for (int fm = 0; fm < 4; ++fm)
                acc[fm][fn] = __builtin_amdgcn_mfma_f32_16x16x32_bf16(al[fm], bh, acc[fm][fn], 0, 0, 0);
        }
        __syncthreads();
    }

    // C/D layout: row = 4*(lane>>4)+r, col = lane&15  [m89-verified]
    const int r4 = (lane >> 4) << 2, cc = lane & 15;
    #pragma unroll
    for (int fm = 0; fm < 4; ++fm) {
        int row = bm + (wm * 4 + fm) * 16 + r4;
        float tv1[4], tv2[4]; int ti1[4], ti2[4];
        #pragma unroll
        for (int r = 0; r < 4; ++r) { tv1[r] = -INFINITY; ti1[r] = INT_MAX;
                                      tv2[r] = -INFINITY; ti2[r] = INT_MAX; }
        #pragma unroll
        for (int fn = 0; fn < 4; ++fn) {
            int col = bn + (wn * 4 + fn) * 16 + cc;
            bool ok = col < NV;
            float bv = ok ? bias[col] : 0.f;
            #pragma unroll
            for (int r = 0; r < 4; ++r) {
                float v = ok ? (acc[fm][fn][r] + bv) : -INFINITY;
                int ci = ok ? col : INT_MAX;
                if (ok) C[(size_t)(row + r) * NV + col] = v;
                if (better(v, ci, tv1[r], ti1[r])) {
                    tv2[r] = tv1[r]; ti2[r] = ti1[r]; tv1[r] = v; ti1[r] = ci;
                } else if (better(v, ci, tv2[r], ti2[r])) { tv2[r] = v; ti2[r] = ci; }
            }
        }
        #pragma unroll
        for (int off = 1; off < 16; off <<= 1) {
            #pragma unroll
            for (int r = 0; r < 4; ++r) {
                float w1 = __shfl_xor(tv1[r], off);
                int   j1 = __shfl_xor(ti1[r], off);
                float w2 = __shfl_xor(tv2[r], off);
                int   j2 = __shfl_xor(ti2[r], off);
                merge2(tv1[r], ti1[r], tv2[r], ti2[r], w1, j1, w2, j2);
            }
        }
        if (cc == 0) {
            #pragma unroll
            for (int r = 0; r < 4; ++r) {
                float4 pk;
                pk.x = tv1[r]; pk.y = __int_as_float(ti1[r]);
                pk.z = tv2[r]; pk.w = __int_as_float(ti2[r]);
                cand[(size_t)(row + r) * NCANDW + blockIdx.x * 2 + wn] = pk;
            }
        }
    }
}

// ---------------- candidate reduce -> exact row top-2 (t < NT-1) -------------
__global__ __launch_bounds__(64)
void cand_reduce_k(const float4* __restrict__ cand, int* __restrict__ top2i)
{
    const int b = blockIdx.x, lane = threadIdx.x;
    float v1 = -INFINITY, v2 = -INFINITY; int i1 = INT_MAX, i2 = INT_MAX;
    for (int s = lane; s < NCANDW; s += 64) {
        float4 pk = cand[(size_t)b * NCANDW + s];
        merge2(v1, i1, v2, i2, pk.x, __float_as_int(pk.y), pk.z, __float_as_int(pk.w));
    }
    #pragma unroll
    for (int off = 1; off < 64; off <<= 1) {
        float w1 = __shfl_xor(v1, off);
        int   j1 = __shfl_xor(i1, off);
        float w2 = __shfl_xor(v2, off);
        int   j2 = __shfl_xor(i2, off);
        merge2(v1, i1, v2, i2, w1, j1, w2, j2);
    }
    if (lane == 0) { top2i[2 * b] = i1; top2i[2 * b + 1] = i2; }
}

// ---------------- receiver gates MFMA: [emb[msg]|h] @ [Wih|Whh]^T + bias -----
// split-bf16 (3 products), tile 128x128, K=768 (k<256: emb/Wih, else h/Whh).
__global__ __launch_bounds__(256)
void recv_mfma(const __bf16* __restrict__ eHi, const __bf16* __restrict__ eLo,
               const int* __restrict__ msg_t,
               const __bf16* __restrict__ hHi, const __bf16* __restrict__ hLo,
               const __bf16* __restrict__ WiHi, const __bf16* __restrict__ WiLo,
               const __bf16* __restrict__ WhHi, const __bf16* __restrict__ WhLo,
               const float* __restrict__ bias, float* __restrict__ gates)
{
    __shared__ __align__(16) char sm[32768];
    __bf16* sAh = (__bf16*)sm;
    __bf16* sAl = (__bf16*)(sm + 8192);
    __bf16* sBh = (__bf16*)(sm + 16384);
    __bf16* sBl = (__bf16*)(sm + 24576);

    const int tid = threadIdx.x;
    const int lane = tid & 63, w = tid >> 6;
    const int wm = w >> 1, wn = w & 1;
    const int bm = blockIdx.y << 7, bn = blockIdx.x << 7;

    int rowA[2], tokA[2], colB[2], goff[2];
    #pragma unroll
    for (int j = 0; j < 2; ++j) {
        int s = tid + j * 256;
        int mf = s >> 6, g = (s >> 4) & 3, row = s & 15;
        rowA[j] = bm + mf * 16 + row;
        tokA[j] = msg_t[rowA[j]];
        colB[j] = bn + mf * 16 + row;
        goff[j] = g * 8;
    }

    f32x4 acc[4][4];
    #pragma unroll
    for (int i = 0; i < 4; ++i)
        #pragma unroll
        for (int j = 0; j < 4; ++j) acc[i][j] = (f32x4){0.f, 0.f, 0.f, 0.f};

    for (int k0 = 0; k0 < NE + NH; k0 += 32) {
        const bool inE = k0 < NE;
        #pragma unroll
        for (int j = 0; j < 2; ++j) {
            int k = k0 + goff[j];
            const __bf16* pah = inE ? eHi + (size_t)tokA[j] * NE + k
                                    : hHi + (size_t)rowA[j] * NH + (k - NE);
            const __bf16* pal = inE ? eLo + (size_t)tokA[j] * NE + k
                                    : hLo + (size_t)rowA[j] * NH + (k - NE);
            const __bf16* pbh = inE ? WiHi + (size_t)colB[j] * NE + k
                                    : WhHi + (size_t)colB[j] * NH + (k - NE);
            const __bf16* pbl = inE ? WiLo + (size_t)colB[j] * NE + k
                                    : WhLo + (size_t)colB[j] * NH + (k - NE);
            *(uint4*)(sAh + (size_t)(tid + j * 256) * 8) = *(const uint4*)pah;
            *(uint4*)(sAl + (size_t)(tid + j * 256) * 8) = *(const uint4*)pal;
            *(uint4*)(sBh + (size_t)(tid + j * 256) * 8) = *(const uint4*)pbh;
            *(uint4*)(sBl + (size_t)(tid + j * 256) * 8) = *(const uint4*)pbl;
        }
        __syncthreads();

        bf16x8 ah[4], al[4];
        #pragma unroll
        for (int f = 0; f < 4; ++f) {
            int base = ((wm * 4 + f) * 64 + lane) * 8;
            ah[f] = *(const bf16x8*)(sAh + base);
            al[f] = *(const bf16x8*)(sAl + base);
        }
        #pragma unroll
        for (int fn = 0; fn < 4; ++fn) {
            int base = ((wn * 4 + fn) * 64 + lane) * 8;
            bf16x8 bh = *(const bf16x8*)(sBh + base);
            bf16x8 bl = *(const bf16x8*)(sBl + base);
            #pragma unroll
            for (int fm = 0; fm < 4; ++fm)
                acc[fm][fn] = __builtin_amdgcn_mfma_f32_16x16x32_bf16(ah[fm], bh, acc[fm][fn], 0, 0, 0);
            #pragma unroll
            for (int fm = 0; fm < 4; ++fm)
                acc[fm][fn] = __builtin_amdgcn_mfma_f32_16x16x32_bf16(ah[fm], bl, acc[fm][fn], 0, 0, 0);
            #pragma unroll
            for (int fm = 0; fm < 4; ++fm)
                acc[fm][fn] = __builtin_amdgcn_mfma_f32_16x16x32_bf16(al[fm], bh, acc[fm][fn], 0, 0, 0);
        }
        __syncthreads();
    }

    const int r4 = (lane >> 4) << 2, cc = lane & 15;
    #pragma unroll
    for (int fm = 0; fm < 4; ++fm) {
        int row = bm + (wm * 4 + fm) * 16 + r4;
        #pragma unroll
        for (int fn = 0; fn < 4; ++fn) {
            int col = bn + (wn * 4 + fn) * 16 + cc;
            float bv = bias[col];
            #pragma unroll
            for (int r = 0; r < 4; ++r)
                gates[(size_t)(row + r) * (4 * NH) + col] = acc[fm][fn][r] + bv;
        }
    }
}

// ---------------- LSTM cell (i,f,g,o); SPLIT: also emit bf16 hi/lo of h ------
template<int SPLIT>
__global__ __launch_bounds__(256)
void lstm_cell_k(const float* __restrict__ gates, float* __restrict__ h,
                 float* __restrict__ c, __bf16* __restrict__ hi,
                 __bf16* __restrict__ lo)
{
    int idx = blockIdx.x * 256 + threadIdx.x;
    int b = idx >> 9;
    int j = idx & (NH - 1);
    const float* g = gates + (size_t)b * (4 * NH);
    float gi = sigf(g[j]);
    float gf = sigf(g[NH + j]);
    float gg = tanhf(g[2 * NH + j]);
    float go = sigf(g[3 * NH + j]);
    float cn = gf * c[idx] + gi * gg;
    c[idx] = cn;
    float hv = go * tanhf(cn);
    h[idx] = hv;
    if (SPLIT) {
        __bf16 hb = (__bf16)hv;
        hi[idx] = hb;
        lo[idx] = (__bf16)(hv - (float)hb);
    }
}

// ---------------- full-scan row top-2 + logsumexp (t = NT-1 only) ------------
__global__ __launch_bounds__(256)
void argmax2_k(const float* __restrict__ logits, int* __restrict__ top2i,
               float* __restrict__ lse)
{
    __shared__ float sv1[256], sv2[256];
    __shared__ int   si1[256], si2[256];
    const int b = blockIdx.x;
    const int tid = threadIdx.x;
    const float* L = logits + (size_t)b * NV;
    float v1 = -INFINITY, v2 = -INFINITY;
    int i1 = INT_MAX, i2 = INT_MAX;
    for (int v = tid; v < NV; v += 256) {
        float x = L[v];
        if (better(x, v, v1, i1)) { v2 = v1; i2 = i1; v1 = x; i1 = v; }
        else if (better(x, v, v2, i2)) { v2 = x; i2 = v; }
    }
    sv1[tid] = v1; si1[tid] = i1; sv2[tid] = v2; si2[tid] = i2;
    __syncthreads();
    for (int s = 128; s > 0; s >>= 1) {
        if (tid < s) {
            float a1 = sv1[tid], a2 = sv2[tid];     int ai1 = si1[tid], ai2 = si2[tid];
            float b1 = sv1[tid+s], b2 = sv2[tid+s]; int bi1 = si1[tid+s], bi2 = si2[tid+s];
            merge2(a1, ai1, a2, ai2, b1, bi1, b2, bi2);
            sv1[tid] = a1; si1[tid] = ai1; sv2[tid] = a2; si2[tid] = ai2;
        }
        __syncthreads();
    }
    if (tid == 0) { top2i[2*b] = si1[0]; top2i[2*b+1] = si2[0]; }
    float m = sv1[0];
    __syncthreads();
    float s = 0.0f;
    for (int v = tid; v < NV; v += 256) s += expf(L[v] - m);
    sv1[tid] = s;
    __syncthreads();
    for (int sh = 128; sh > 0; sh >>= 1) {
        if (tid < sh) sv1[tid] += sv1[tid + sh];
        __syncthreads();
    }
    if (tid == 0) lse[b] = m + logf(sv1[0]);
}

// ---------------- fp64 rescore of top-2 -> exact token -----------------------
template<int LAST>
__global__ __launch_bounds__(64)
void rescore_k(const float* __restrict__ h, const float* __restrict__ Wpr,
               const float* __restrict__ bpr, const float* __restrict__ logits,
               const int* __restrict__ top2i, const float* __restrict__ lse,
               int* __restrict__ msg_t, float* __restrict__ out_msg,
               float* __restrict__ lp, int t)
{
    const int b = blockIdx.x;
    const int tid = threadIdx.x;
    const int i1 = top2i[2*b], i2 = top2i[2*b+1];
    const float* hr = h + (size_t)b * NH;
    const float* w1 = Wpr + (size_t)i1 * NH;
    const float* w2 = Wpr + (size_t)i2 * NH;
    double s1 = 0.0, s2 = 0.0;
    for (int k = tid; k < NH; k += 64) {
        double hv = (double)hr[k];
        s1 += hv * (double)w1[k];
        s2 += hv * (double)w2[k];
    }
    #pragma unroll
    for (int off = 32; off > 0; off >>= 1) {
        s1 += __shfl_down(s1, off);
        s2 += __shfl_down(s2, off);
    }
    if (tid == 0) {
        s1 += (double)bpr[i1];
        s2 += (double)bpr[i2];
        int w = (s1 > s2 || (s1 == s2 && i1 < i2)) ? i1 : i2;
        msg_t[b] = w;
        out_msg[(size_t)b * NT + t] = (float)w;
        if (LAST) lp[b] = logits[(size_t)b * NV + w] - lse[b];
    }
}

__global__ void init_idx_k(const int* __restrict__ start, int* __restrict__ idx)
{
    int b = blockIdx.x * 256 + threadIdx.x;
    if (b < NB) idx[b] = start[0];
}

__global__ void bias_comb_k(const float* __restrict__ a, const float* __restrict__ b,
                            float* __restrict__ o)
{
    int n = blockIdx.x * 256 + threadIdx.x;
    if (n < 4 * NH) o[n] = a[n] + b[n];
}

// hsum[b] = sum_n hinge[b,n] * (-lp[n])  (lp broadcasts over LAST axis)
__global__ __launch_bounds__(256)
void loss_row_k(const float* __restrict__ scores, const float* __restrict__ lp,
                float* __restrict__ hsum, float* __restrict__ accb)
{
    __shared__ float red[256];
    const int b = blockIdx.x;
    const int tid = threadIdx.x;
    const float* ts = scores + (size_t)b * NB;
    const float* d0 = scores + (size_t)NB * NB * 1 + (size_t)b * NB;
    const float* d1 = scores + (size_t)NB * NB * 2 + (size_t)b * NB;
    const float* d2 = scores + (size_t)NB * NB * 3 + (size_t)b * NB;
    float hs = 0.f, t0 = 0.f, s0 = 0.f, s1 = 0.f, s2 = 0.f;
    for (int n = tid; n < NB; n += 256) {
        float tv = ts[n], a = d0[n], bb = d1[n], cc = d2[n];
        float hinge_bn = fmaxf(0.f, 1.f - tv + a) + fmaxf(0.f, 1.f - tv + bb)
                       + fmaxf(0.f, 1.f - tv + cc);
        hs += hinge_bn * (-lp[n]);
        t0 += expf(tv); s0 += expf(a); s1 += expf(bb); s2 += expf(cc);
    }
    float vals[5] = {hs, t0, s0, s1, s2};
    float outv[5];
    for (int i = 0; i < 5; ++i) {
        red[tid] = vals[i]; __syncthreads();
        for (int s = 128; s > 0; s >>= 1) {
            if (tid < s) red[tid] += red[tid + s];
            __syncthreads();
        }
        outv[i] = red[0]; __syncthreads();
    }
    if (tid == 0) {
        hsum[b] = outv[0];
        accb[b] = (outv[1] >= outv[2] && outv[1] >= outv[3] && outv[1] >= outv[4]) ? 1.0f : 0.0f;
    }
}

__global__ __launch_bounds__(256)
void loss_final_k(const float* __restrict__ hsum, const float* __restrict__ accb,
                  float* __restrict__ out)
{
    __shared__ float red[256];
    const int tid = threadIdx.x;
    float s = 0.f, a = 0.f;
    for (int b = tid; b < NB; b += 256) { s += hsum[b]; a += accb[b]; }
    red[tid] = s; __syncthreads();
    for (int sh = 128; sh > 0; sh >>= 1) { if (tid < sh) red[tid] += red[tid + sh]; __syncthreads(); }
    s = red[0]; __syncthreads();
    red[tid] = a; __syncthreads();
    for (int sh = 128; sh > 0; sh >>= 1) { if (tid < sh) red[tid] += red[tid + sh]; __syncthreads(); }
    a = red[0];
    if (tid == 0) {
        out[0] = s / (float)((size_t)NB * NB);
        out[1] = a / (float)NB;
    }
}

extern "C" void kernel_launch(void* const* d_in, const int* in_sizes, int n_in,
                              void* d_out, int out_size, void* d_ws, size_t ws_size,
                              hipStream_t stream)
{
    const float* target   = (const float*)d_in[0];
    const float* distract = (const float*)d_in[1];
    const float* sWaff = (const float*)d_in[2];
    const float* sbaff = (const float*)d_in[3];
    const float* sWih  = (const float*)d_in[4];
    const float* sWhh  = (const float*)d_in[5];
    const float* sbih  = (const float*)d_in[6];
    const float* sbhh  = (const float*)d_in[7];
    const float* semb  = (const float*)d_in[8];
    const float* sWpr  = (const float*)d_in[9];
    const float* sbpr  = (const float*)d_in[10];
    const float* remb  = (const float*)d_in[11];
    const float* rWih  = (const float*)d_in[12];
    const float* rWhh  = (const float*)d_in[13];
    const float* rbih  = (const float*)d_in[14];
    const float* rbhh  = (const float*)d_in[15];
    const float* rWaff = (const float*)d_in[16];
    const float* rbaff = (const float*)d_in[17];
    const int*   start = (const int*)d_in[18];
    (void)in_sizes; (void)n_in; (void)out_size; (void)ws_size;

    float* out = (float*)d_out;
    float* ws  = (float*)d_ws;

    // workspace layout (floats); ~26M floats ~= 104 MB
    size_t o = 0;
    float* logits = ws + o; o += (size_t)NB * NV;       // reused as scores[4][NB][NB]
    float* gates  = ws + o; o += (size_t)NB * 4 * NH;   // reused as r_transform
    float* h_s    = ws + o; o += (size_t)NB * NH;
    float* c_s    = ws + o; o += (size_t)NB * NH;
    float* h_r    = ws + o; o += (size_t)NB * NH;
    float* c_r    = ws + o; o += (size_t)NB * NH;
    float* lp     = ws + o; o += NB;
    float* lse    = ws + o; o += NB;
    float* bias_s = ws + o; o += 4 * NH;
    float* bias_r = ws + o; o += 4 * NH;
    float* hsum   = ws + o; o += NB;
    float* accb   = ws + o; o += NB;
    int* msg      = (int*)(ws + o); o += (size_t)NB * NT;
    int* idx0     = (int*)(ws + o); o += NB;
    int* top2i    = (int*)(ws + o); o += 2 * NB;
    __bf16* WHi   = (__bf16*)(ws + o); o += (size_t)NV * NH / 2;
    __bf16* WLo   = (__bf16*)(ws + o); o += (size_t)NV * NH / 2;
    __bf16* hHi   = (__bf16*)(ws + o); o += (size_t)NB * NH / 2;
    __bf16* hLo   = (__bf16*)(ws + o); o += (size_t)NB * NH / 2;
    float4* cand  = (float4*)(ws + o); o += (size_t)NB * NCANDW * 4;
    __bf16* WiHi  = (__bf16*)(ws + o); o += (size_t)(4*NH) * NE / 2;
    __bf16* WiLo  = (__bf16*)(ws + o); o += (size_t)(4*NH) * NE / 2;
    __bf16* WhHi  = (__bf16*)(ws + o); o += (size_t)(4*NH) * NH / 2;
    __bf16* WhLo  = (__bf16*)(ws + o); o += (size_t)(4*NH) * NH / 2;
    __bf16* eHi   = (__bf16*)(ws + o); o += (size_t)NV * NE / 2;
    __bf16* eLo   = (__bf16*)(ws + o); o += (size_t)NV * NE / 2;
    __bf16* hrHi  = (__bf16*)(ws + o); o += (size_t)NB * NH / 2;
    __bf16* hrLo  = (__bf16*)(ws + o); o += (size_t)NB * NH / 2;

    bias_comb_k<<<8, 256, 0, stream>>>(sbih, sbhh, bias_s);
    bias_comb_k<<<8, 256, 0, stream>>>(rbih, rbhh, bias_r);
    init_idx_k<<<4, 256, 0, stream>>>(start, idx0);
    hipMemsetAsync(c_s, 0, (size_t)NB * NH * 4, stream);
    hipMemsetAsync(h_r, 0, (size_t)NB * NH * 4, stream);
    hipMemsetAsync(c_r, 0, (size_t)NB * NH * 4, stream);
    hipMemsetAsync(hrHi, 0, (size_t)NB * NH * 2, stream);
    hipMemsetAsync(hrLo, 0, (size_t)NB * NH * 2, stream);

    // weight/embedding splits (once per launch)
    split_k<<<(NV * NH + 255) / 256, 256, 0, stream>>>(sWpr, WHi, WLo, NV * NH);
    split_k<<<(4*NH*NE + 255) / 256, 256, 0, stream>>>(rWih, WiHi, WiLo, 4*NH*NE);
    split_k<<<(4*NH*NH + 255) / 256, 256, 0, stream>>>(rWhh, WhHi, WhLo, 4*NH*NH);
    split_k<<<(NV * NE + 255) / 256, 256, 0, stream>>>(remb, eHi, eLo, NV * NE);

    // h0 = target @ s_W_aff^T + s_b_aff  (32x128 tile, bit-identical chain)
    h0_gemm<<<dim3(NH/128, NB/32), 256, 0, stream>>>(
        target, sWaff, sbaff, h_s, NB, NH, NF);

    // ---- Sender ----
    const int* cur = idx0;
    for (int t = 0; t < NT; ++t) {
        gemm512<0,1,0,1><<<dim3(4*NH/128, NB/64), 512, 0, stream>>>(
            semb, nullptr, cur, sWih, bias_s, gates, NB, 4*NH, NE);
        gemm512<1,0,0,0><<<dim3(4*NH/128, NB/64), 512, 0, stream>>>(
            h_s, nullptr, nullptr, sWhh, nullptr, gates, NB, 4*NH, NH);
        lstm_cell_k<1><<<NB*NH/256, 256, 0, stream>>>(gates, h_s, c_s, hHi, hLo);
        logits_mfma<<<dim3(NBX, NB / 128), 256, 0, stream>>>(
            hHi, hLo, WHi, WLo, sbpr, logits, cand);
        if (t == NT - 1) {
            argmax2_k<<<NB, 256, 0, stream>>>(logits, top2i, lse);
            rescore_k<1><<<NB, 64, 0, stream>>>(h_s, sWpr, sbpr, logits, top2i, lse,
                                                msg + (size_t)t*NB, out + 2, lp, t);
        } else {
            cand_reduce_k<<<NB, 64, 0, stream>>>(cand, top2i);
            rescore_k<0><<<NB, 64, 0, stream>>>(h_s, sWpr, sbpr, logits, top2i, lse,
                                                msg + (size_t)t*NB, out + 2, lp, t);
        }
        cur = msg + (size_t)t * NB;
    }

    // ---- Receiver (split-bf16 MFMA gates; loss path) ----
    for (int t = 0; t < NT; ++t) {
        recv_mfma<<<dim3(4*NH/128, NB/128), 256, 0, stream>>>(
            eHi, eLo, msg + (size_t)t*NB, hrHi, hrLo,
            WiHi, WiLo, WhHi, WhLo, bias_r, gates);
        lstm_cell_k<1><<<NB*NH/256, 256, 0, stream>>>(gates, h_r, c_r, hrHi, hrLo);
    }

    // r_transform = h_r @ r_W_aff^T + r_b_aff
    float* rtr = gates;
    gemm512<0,1,0,0><<<dim3(NF/128, NB/64), 512, 0, stream>>>(
        h_r, nullptr, nullptr, rWaff, rbaff, rtr, NB, NF, NH);

    // scores[z] : z=0 target, z=1..3 distractors (batched via grid.z)
    float* scores = logits;
    gemm512<0,0,1,0><<<dim3(NB/128, NB/64, 1 + ND), 512, 0, stream>>>(
        target, distract, nullptr, rtr, nullptr, scores, NB, NB, NF);

    loss_row_k<<<NB, 256, 0, stream>>>(scores, lp, hsum, accb);
    loss_final_k<<<1, 256, 0, stream>>>(hsum, accb, out);
}

// Round 13
// 4971.433 us; speedup vs baseline: 1.1936x; 1.1936x over previous
//
#include <hip/hip_runtime.h>
#include <math.h>
#include <limits.h>

#define NB 1024   // batch
#define NF 2048   // features
#define NV 10000  // vocab
#define NE 256    // embed
#define NH 512    // hidden
#define ND 3      // distractors
#define NT 20     // max sentence length
#define NBX ((NV + 127) / 128)   // 79 logits col-blocks

typedef __bf16 bf16x8 __attribute__((ext_vector_type(8)));
typedef float  f32x4  __attribute__((ext_vector_type(4)));

__device__ __forceinline__ float sigf(float x) { return 1.0f / (1.0f + expf(-x)); }
__device__ __forceinline__ bool better(float v, int i, float w, int j) {
    return (v > w) || (v == w && i < j);
}
// merge sorted pair (w1>=w2) into running top-2 (v1,i1,v2,i2)
__device__ __forceinline__ void merge2(float& v1, int& i1, float& v2, int& i2,
                                       float w1, int j1, float w2, int j2) {
    if (better(w1, j1, v1, i1)) {
        if (better(v1, i1, w2, j2)) { v2 = v1; i2 = i1; }
        else                        { v2 = w2; i2 = j2; }
        v1 = w1; i1 = j1;
    } else if (better(w1, j1, v2, i2)) { v2 = w1; i2 = j1; }
}

// ---------------- fp32 GEMM: C = A[M,K] @ B[N,K]^T (+bias) (+accum) ----------
// tile 64(M)x128(N), BK=16, 512 threads, 4x4/thread. Ascending-k fmaf chain ==
// validated baseline -> sender h BIT-IDENTICAL. GATHER: A row r = A[gidx[r]*K].
template<int ACCUM, int BIAS, int ZMODE, int GATHER>
__global__ __launch_bounds__(512)
void gemm512(const float* __restrict__ A, const float* __restrict__ A2,
             const int* __restrict__ gidx,
             const float* __restrict__ Bm, const float* __restrict__ bias,
             float* __restrict__ C, int M, int N, int K)
{
    __shared__ float As[16][68];
    __shared__ float Bs[16][132];
    const int tid = threadIdx.x;
    const int bn = blockIdx.x << 7;
    const int bm = blockIdx.y << 6;

    const float* Ause = A;
    if (ZMODE) {
        if (blockIdx.z > 0) Ause = A2 + (size_t)(blockIdx.z - 1) * M * K;
        C += (size_t)blockIdx.z * M * N;
    }

    const int abr = tid & 63;
    const int abk = ((tid >> 6) & 3) << 2;
    const int bbr = tid & 127;
    const int bbk = (tid >> 7) << 2;
    const int tx = tid & 31, ty = tid >> 5;
    const int m0 = ty << 2, n0 = tx << 2;

    const float* Arow = nullptr;
    if (tid < 256) {
        int r = bm + abr;
        Arow = GATHER ? (A + (size_t)gidx[r] * K) : (Ause + (size_t)r * K);
    }
    const float* Brow = Bm + (size_t)(bn + bbr) * K;

    float acc[4][4];
    #pragma unroll
    for (int i = 0; i < 4; ++i)
        #pragma unroll
        for (int j = 0; j < 4; ++j) acc[i][j] = 0.f;

    for (int k0 = 0; k0 < K; k0 += 16) {
        if (tid < 256) {
            float4 av = *(const float4*)(Arow + k0 + abk);
            As[abk + 0][abr] = av.x; As[abk + 1][abr] = av.y;
            As[abk + 2][abr] = av.z; As[abk + 3][abr] = av.w;
        }
        float4 bv = *(const float4*)(Brow + k0 + bbk);
        Bs[bbk + 0][bbr] = bv.x; Bs[bbk + 1][bbr] = bv.y;
        Bs[bbk + 2][bbr] = bv.z; Bs[bbk + 3][bbr] = bv.w;
        __syncthreads();
        #pragma unroll
        for (int k = 0; k < 16; ++k) {
            float4 xa = *(const float4*)&As[k][m0];
            float4 xb = *(const float4*)&Bs[k][n0];
            float ar[4] = {xa.x, xa.y, xa.z, xa.w};
            float br[4] = {xb.x, xb.y, xb.z, xb.w};
            #pragma unroll
            for (int i = 0; i < 4; ++i)
                #pragma unroll
                for (int j = 0; j < 4; ++j)
                    acc[i][j] = fmaf(ar[i], br[j], acc[i][j]);
        }
        __syncthreads();
    }
    #pragma unroll
    for (int i = 0; i < 4; ++i) {
        int row = bm + m0 + i;
        #pragma unroll
        for (int j = 0; j < 4; ++j) {
            int col = bn + n0 + j;
            float v = acc[i][j];
            if (BIAS) v += bias[col];
            float* p = C + (size_t)row * N + col;
            if (ACCUM) v += *p;
            *p = v;
        }
    }
}

// ---------------- h0: 32(M)x128(N) tile fp32 (2x block count for M=1024,N=512)
// Same ascending-k fmaf chain per output element -> bit-identical h0.
__global__ __launch_bounds__(256)
void h0_gemm(const float* __restrict__ A, const float* __restrict__ Bm,
             const float* __restrict__ bias, float* __restrict__ C,
             int M, int N, int K)
{
    __shared__ float As[16][36];
    __shared__ float Bs[16][132];
    const int tid = threadIdx.x;
    const int bn = blockIdx.x << 7;
    const int bm = blockIdx.y << 5;

    const int abr = tid & 31;
    const int abk = ((tid >> 5) & 3) << 2;   // threads 0..127 stage A
    const int bbr = tid & 127;
    const int bbk = (tid >> 7) << 3;         // 0 or 8, two float4 each
    const int tx = tid & 31, ty = tid >> 5;
    const int m0 = ty << 2, n0 = tx << 2;

    const float* Arow = A + (size_t)(bm + abr) * K;
    const float* Brow = Bm + (size_t)(bn + bbr) * K;

    float acc[4][4];
    #pragma unroll
    for (int i = 0; i < 4; ++i)
        #pragma unroll
        for (int j = 0; j < 4; ++j) acc[i][j] = 0.f;

    for (int k0 = 0; k0 < K; k0 += 16) {
        if (tid < 128) {
            float4 av = *(const float4*)(Arow + k0 + abk);
            As[abk + 0][abr] = av.x; As[abk + 1][abr] = av.y;
            As[abk + 2][abr] = av.z; As[abk + 3][abr] = av.w;
        }
        float4 b0 = *(const float4*)(Brow + k0 + bbk);
        float4 b1 = *(const float4*)(Brow + k0 + bbk + 4);
        Bs[bbk + 0][bbr] = b0.x; Bs[bbk + 1][bbr] = b0.y;
        Bs[bbk + 2][bbr] = b0.z; Bs[bbk + 3][bbr] = b0.w;
        Bs[bbk + 4][bbr] = b1.x; Bs[bbk + 5][bbr] = b1.y;
        Bs[bbk + 6][bbr] = b1.z; Bs[bbk + 7][bbr] = b1.w;
        __syncthreads();
        #pragma unroll
        for (int k = 0; k < 16; ++k) {
            float4 xa = *(const float4*)&As[k][m0];
            float4 xb = *(const float4*)&Bs[k][n0];
            float ar[4] = {xa.x, xa.y, xa.z, xa.w};
            float br[4] = {xb.x, xb.y, xb.z, xb.w};
            #pragma unroll
            for (int i = 0; i < 4; ++i)
                #pragma unroll
                for (int j = 0; j < 4; ++j)
                    acc[i][j] = fmaf(ar[i], br[j], acc[i][j]);
        }
        __syncthreads();
    }
    #pragma unroll
    for (int i = 0; i < 4; ++i) {
        int row = bm + m0 + i;
        #pragma unroll
        for (int j = 0; j < 4; ++j) {
            int col = bn + n0 + j;
            C[(size_t)row * N + col] = acc[i][j] + bias[col];
        }
    }
}

// ---------------- split fp32 -> hi/lo bf16 planes ----------------------------
__global__ void split_k(const float* __restrict__ x, __bf16* __restrict__ hi,
                        __bf16* __restrict__ lo, int n)
{
    int i = blockIdx.x * 256 + threadIdx.x;
    if (i < n) {
        float v = x[i];
        __bf16 h = (__bf16)v;
        hi[i] = h;
        lo[i] = (__bf16)(v - (float)h);
    }
}

// ---------------- logits: C[NB,NV] = h[NB,NH] @ W[NV,NH]^T + bias ------------
// split-bf16 MFMA (3 products). Tile 128x128, BK=32, 4 waves 2x2, fragment-major
// LDS. r10 form: plain C-store epilogue (fused top-2 REVERTED -- r11 A/B showed
// +548us regression, suspected occupancy loss from epilogue register pressure).
__global__ __launch_bounds__(256)
void logits_mfma(const __bf16* __restrict__ Ahi, const __bf16* __restrict__ Alo,
                 const __bf16* __restrict__ Bhi, const __bf16* __restrict__ Blo,
                 const float* __restrict__ bias, float* __restrict__ C)
{
    __shared__ __align__(16) char sm[32768];
    __bf16* sAh = (__bf16*)sm;
    __bf16* sAl = (__bf16*)(sm + 8192);
    __bf16* sBh = (__bf16*)(sm + 16384);
    __bf16* sBl = (__bf16*)(sm + 24576);

    const int tid = threadIdx.x;
    const int lane = tid & 63, w = tid >> 6;
    const int wm = w >> 1, wn = w & 1;
    const int bm = blockIdx.y << 7, bn = blockIdx.x << 7;

    size_t ga[2], gb[2];
    #pragma unroll
    for (int j = 0; j < 2; ++j) {
        int s = tid + j * 256;
        int mf = s >> 6, g = (s >> 4) & 3, row = s & 15;
        ga[j] = (size_t)(bm + mf * 16 + row) * NH + g * 8;
        int n = bn + mf * 16 + row;
        if (n >= NV) n = 0;
        gb[j] = (size_t)n * NH + g * 8;
    }

    f32x4 acc[4][4];
    #pragma unroll
    for (int i = 0; i < 4; ++i)
        #pragma unroll
        for (int j = 0; j < 4; ++j) acc[i][j] = (f32x4){0.f, 0.f, 0.f, 0.f};

    for (int k0 = 0; k0 < NH; k0 += 32) {
        uint4 vah0 = *(const uint4*)(Ahi + ga[0] + k0);
        uint4 vah1 = *(const uint4*)(Ahi + ga[1] + k0);
        uint4 val0 = *(const uint4*)(Alo + ga[0] + k0);
        uint4 val1 = *(const uint4*)(Alo + ga[1] + k0);
        uint4 vbh0 = *(const uint4*)(Bhi + gb[0] + k0);
        uint4 vbh1 = *(const uint4*)(Bhi + gb[1] + k0);
        uint4 vbl0 = *(const uint4*)(Blo + gb[0] + k0);
        uint4 vbl1 = *(const uint4*)(Blo + gb[1] + k0);
        *(uint4*)(sAh + (size_t)tid * 8)         = vah0;
        *(uint4*)(sAh + (size_t)(tid + 256) * 8) = vah1;
        *(uint4*)(sAl + (size_t)tid * 8)         = val0;
        *(uint4*)(sAl + (size_t)(tid + 256) * 8) = val1;
        *(uint4*)(sBh + (size_t)tid * 8)         = vbh0;
        *(uint4*)(sBh + (size_t)(tid + 256) * 8) = vbh1;
        *(uint4*)(sBl + (size_t)tid * 8)         = vbl0;
        *(uint4*)(sBl + (size_t)(tid + 256) * 8) = vbl1;
        __syncthreads();

        bf16x8 ah[4], al[4];
        #pragma unroll
        for (int f = 0; f < 4; ++f) {
            int base = ((wm * 4 + f) * 64 + lane) * 8;
            ah[f] = *(const bf16x8*)(sAh + base);
            al[f] = *(const bf16x8*)(sAl + base);
        }
        #pragma unroll
        for (int fn = 0; fn < 4; ++fn) {
            int base = ((wn * 4 + fn) * 64 + lane) * 8;
            bf16x8 bh = *(const bf16x8*)(sBh + base);
            bf16x8 bl = *(const bf16x8*)(sBl + base);
            #pragma unroll
            for (int fm = 0; fm < 4; ++fm)
                acc[fm][fn] = __builtin_amdgcn_mfma_f32_16x16x32_bf16(ah[fm], bh, acc[fm][fn], 0, 0, 0);
            #pragma unroll
            for (int fm = 0; fm < 4; ++fm)
                acc[fm][fn] = __builtin_amdgcn_mfma_f32_16x16x32_bf16(ah[fm], bl, acc[fm][fn], 0, 0, 0);
            #pragma unroll
            for (int fm = 0; fm < 4; ++fm)
                acc[fm][fn] = __builtin_amdgcn_mfma_f32_16x16x32_bf16(al[fm], bh, acc[fm][fn], 0, 0, 0);
        }
        __syncthreads();
    }

    // C/D layout: row = 4*(lane>>4)+r, col = lane&15  [m89-verified]
    const int r4 = (lane >> 4) << 2, cc = lane & 15;
    #pragma unroll
    for (int fm = 0; fm < 4; ++fm) {
        int row = bm + (wm * 4 + fm) * 16 + r4;
        #pragma unroll
        for (int fn = 0; fn < 4; ++fn) {
            int col = bn + (wn * 4 + fn) * 16 + cc;
            if (col < NV) {
                float bv = bias[col];
                #pragma unroll
                for (int r = 0; r < 4; ++r)
                    C[(size_t)(row + r) * NV + col] = acc[fm][fn][r] + bv;
            }
        }
    }
}

// ---------------- receiver gates MFMA: [emb[msg]|h] @ [Wih|Whh]^T + bias -----
// split-bf16 (3 products), tile 128x128, K=768 (k<256: emb/Wih, else h/Whh).
__global__ __launch_bounds__(256)
void recv_mfma(const __bf16* __restrict__ eHi, const __bf16* __restrict__ eLo,
               const int* __restrict__ msg_t,
               const __bf16* __restrict__ hHi, const __bf16* __restrict__ hLo,
               const __bf16* __restrict__ WiHi, const __bf16* __restrict__ WiLo,
               const __bf16* __restrict__ WhHi, const __bf16* __restrict__ WhLo,
               const float* __restrict__ bias, float* __restrict__ gates)
{
    __shared__ __align__(16) char sm[32768];
    __bf16* sAh = (__bf16*)sm;
    __bf16* sAl = (__bf16*)(sm + 8192);
    __bf16* sBh = (__bf16*)(sm + 16384);
    __bf16* sBl = (__bf16*)(sm + 24576);

    const int tid = threadIdx.x;
    const int lane = tid & 63, w = tid >> 6;
    const int wm = w >> 1, wn = w & 1;
    const int bm = blockIdx.y << 7, bn = blockIdx.x << 7;

    int rowA[2], tokA[2], colB[2], goff[2];
    #pragma unroll
    for (int j = 0; j < 2; ++j) {
        int s = tid + j * 256;
        int mf = s >> 6, g = (s >> 4) & 3, row = s & 15;
        rowA[j] = bm + mf * 16 + row;
        tokA[j] = msg_t[rowA[j]];
        colB[j] = bn + mf * 16 + row;
        goff[j] = g * 8;
    }

    f32x4 acc[4][4];
    #pragma unroll
    for (int i = 0; i < 4; ++i)
        #pragma unroll
        for (int j = 0; j < 4; ++j) acc[i][j] = (f32x4){0.f, 0.f, 0.f, 0.f};

    for (int k0 = 0; k0 < NE + NH; k0 += 32) {
        const bool inE = k0 < NE;
        #pragma unroll
        for (int j = 0; j < 2; ++j) {
            int k = k0 + goff[j];
            const __bf16* pah = inE ? eHi + (size_t)tokA[j] * NE + k
                                    : hHi + (size_t)rowA[j] * NH + (k - NE);
            const __bf16* pal = inE ? eLo + (size_t)tokA[j] * NE + k
                                    : hLo + (size_t)rowA[j] * NH + (k - NE);
            const __bf16* pbh = inE ? WiHi + (size_t)colB[j] * NE + k
                                    : WhHi + (size_t)colB[j] * NH + (k - NE);
            const __bf16* pbl = inE ? WiLo + (size_t)colB[j] * NE + k
                                    : WhLo + (size_t)colB[j] * NH + (k - NE);
            *(uint4*)(sAh + (size_t)(tid + j * 256) * 8) = *(const uint4*)pah;
            *(uint4*)(sAl + (size_t)(tid + j * 256) * 8) = *(const uint4*)pal;
            *(uint4*)(sBh + (size_t)(tid + j * 256) * 8) = *(const uint4*)pbh;
            *(uint4*)(sBl + (size_t)(tid + j * 256) * 8) = *(const uint4*)pbl;
        }
        __syncthreads();

        bf16x8 ah[4], al[4];
        #pragma unroll
        for (int f = 0; f < 4; ++f) {
            int base = ((wm * 4 + f) * 64 + lane) * 8;
            ah[f] = *(const bf16x8*)(sAh + base);
            al[f] = *(const bf16x8*)(sAl + base);
        }
        #pragma unroll
        for (int fn = 0; fn < 4; ++fn) {
            int base = ((wn * 4 + fn) * 64 + lane) * 8;
            bf16x8 bh = *(const bf16x8*)(sBh + base);
            bf16x8 bl = *(const bf16x8*)(sBl + base);
            #pragma unroll
            for (int fm = 0; fm < 4; ++fm)
                acc[fm][fn] = __builtin_amdgcn_mfma_f32_16x16x32_bf16(ah[fm], bh, acc[fm][fn], 0, 0, 0);
            #pragma unroll
            for (int fm = 0; fm < 4; ++fm)
                acc[fm][fn] = __builtin_amdgcn_mfma_f32_16x16x32_bf16(ah[fm], bl, acc[fm][fn], 0, 0, 0);
            #pragma unroll
            for (int fm = 0; fm < 4; ++fm)
                acc[fm][fn] = __builtin_amdgcn_mfma_f32_16x16x32_bf16(al[fm], bh, acc[fm][fn], 0, 0, 0);
        }
        __syncthreads();
    }

    const int r4 = (lane >> 4) << 2, cc = lane & 15;
    #pragma unroll
    for (int fm = 0; fm < 4; ++fm) {
        int row = bm + (wm * 4 + fm) * 16 + r4;
        #pragma unroll
        for (int fn = 0; fn < 4; ++fn) {
            int col = bn + (wn * 4 + fn) * 16 + cc;
            float bv = bias[col];
            #pragma unroll
            for (int r = 0; r < 4; ++r)
                gates[(size_t)(row + r) * (4 * NH) + col] = acc[fm][fn][r] + bv;
        }
    }
}

// ---------------- LSTM cell (i,f,g,o); SPLIT: also emit bf16 hi/lo of h ------
template<int SPLIT>
__global__ __launch_bounds__(256)
void lstm_cell_k(const float* __restrict__ gates, float* __restrict__ h,
                 float* __restrict__ c, __bf16* __restrict__ hi,
                 __bf16* __restrict__ lo)
{
    int idx = blockIdx.x * 256 + threadIdx.x;
    int b = idx >> 9;
    int j = idx & (NH - 1);
    const float* g = gates + (size_t)b * (4 * NH);
    float gi = sigf(g[j]);
    float gf = sigf(g[NH + j]);
    float gg = tanhf(g[2 * NH + j]);
    float go = sigf(g[3 * NH + j]);
    float cn = gf * c[idx] + gi * gg;
    c[idx] = cn;
    float hv = go * tanhf(cn);
    h[idx] = hv;
    if (SPLIT) {
        __bf16 hb = (__bf16)hv;
        hi[idx] = hb;
        lo[idx] = (__bf16)(hv - (float)hb);
    }
}

// ---------------- row top-2 (+LAST: logsumexp) -------------------------------
template<int LAST>
__global__ __launch_bounds__(256)
void argmax2_k(const float* __restrict__ logits, int* __restrict__ top2i,
               float* __restrict__ lse)
{
    __shared__ float sv1[256], sv2[256];
    __shared__ int   si1[256], si2[256];
    const int b = blockIdx.x;
    const int tid = threadIdx.x;
    const float* L = logits + (size_t)b * NV;
    float v1 = -INFINITY, v2 = -INFINITY;
    int i1 = INT_MAX, i2 = INT_MAX;
    for (int v = tid; v < NV; v += 256) {
        float x = L[v];
        if (better(x, v, v1, i1)) { v2 = v1; i2 = i1; v1 = x; i1 = v; }
        else if (better(x, v, v2, i2)) { v2 = x; i2 = v; }
    }
    sv1[tid] = v1; si1[tid] = i1; sv2[tid] = v2; si2[tid] = i2;
    __syncthreads();
    for (int s = 128; s > 0; s >>= 1) {
        if (tid < s) {
            float a1 = sv1[tid], a2 = sv2[tid];     int ai1 = si1[tid], ai2 = si2[tid];
            merge2(a1, ai1, a2, ai2, sv1[tid+s], si1[tid+s], sv2[tid+s], si2[tid+s]);
            sv1[tid] = a1; si1[tid] = ai1; sv2[tid] = a2; si2[tid] = ai2;
        }
        __syncthreads();
    }
    if (tid == 0) { top2i[2*b] = si1[0]; top2i[2*b+1] = si2[0]; }
    if (LAST) {
        float m = sv1[0];
        __syncthreads();
        float s = 0.0f;
        for (int v = tid; v < NV; v += 256) s += expf(L[v] - m);
        sv1[tid] = s;
        __syncthreads();
        for (int sh = 128; sh > 0; sh >>= 1) {
            if (tid < sh) sv1[tid] += sv1[tid + sh];
            __syncthreads();
        }
        if (tid == 0) lse[b] = m + logf(sv1[0]);
    }
}

// ---------------- fp64 rescore of top-2 -> exact token -----------------------
template<int LAST>
__global__ __launch_bounds__(64)
void rescore_k(const float* __restrict__ h, const float* __restrict__ Wpr,
               const float* __restrict__ bpr, const float* __restrict__ logits,
               const int* __restrict__ top2i, const float* __restrict__ lse,
               int* __restrict__ msg_t, float* __restrict__ out_msg,
               float* __restrict__ lp, int t)
{
    const int b = blockIdx.x;
    const int tid = threadIdx.x;
    const int i1 = top2i[2*b], i2 = top2i[2*b+1];
    const float* hr = h + (size_t)b * NH;
    const float* w1 = Wpr + (size_t)i1 * NH;
    const float* w2 = Wpr + (size_t)i2 * NH;
    double s1 = 0.0, s2 = 0.0;
    for (int k = tid; k < NH; k += 64) {
        double hv = (double)hr[k];
        s1 += hv * (double)w1[k];
        s2 += hv * (double)w2[k];
    }
    #pragma unroll
    for (int off = 32; off > 0; off >>= 1) {
        s1 += __shfl_down(s1, off);
        s2 += __shfl_down(s2, off);
    }
    if (tid == 0) {
        s1 += (double)bpr[i1];
        s2 += (double)bpr[i2];
        int w = (s1 > s2 || (s1 == s2 && i1 < i2)) ? i1 : i2;
        msg_t[b] = w;
        out_msg[(size_t)b * NT + t] = (float)w;
        if (LAST) lp[b] = logits[(size_t)b * NV + w] - lse[b];
    }
}

__global__ void init_idx_k(const int* __restrict__ start, int* __restrict__ idx)
{
    int b = blockIdx.x * 256 + threadIdx.x;
    if (b < NB) idx[b] = start[0];
}

__global__ void bias_comb_k(const float* __restrict__ a, const float* __restrict__ b,
                            float* __restrict__ o)
{
    int n = blockIdx.x * 256 + threadIdx.x;
    if (n < 4 * NH) o[n] = a[n] + b[n];
}

// hsum[b] = sum_n hinge[b,n] * (-lp[n])  (lp broadcasts over LAST axis)
__global__ __launch_bounds__(256)
void loss_row_k(const float* __restrict__ scores, const float* __restrict__ lp,
                float* __restrict__ hsum, float* __restrict__ accb)
{
    __shared__ float red[256];
    const int b = blockIdx.x;
    const int tid = threadIdx.x;
    const float* ts = scores + (size_t)b * NB;
    const float* d0 = scores + (size_t)NB * NB * 1 + (size_t)b * NB;
    const float* d1 = scores + (size_t)NB * NB * 2 + (size_t)b * NB;
    const float* d2 = scores + (size_t)NB * NB * 3 + (size_t)b * NB;
    float hs = 0.f, t0 = 0.f, s0 = 0.f, s1 = 0.f, s2 = 0.f;
    for (int n = tid; n < NB; n += 256) {
        float tv = ts[n], a = d0[n], bb = d1[n], cc = d2[n];
        float hinge_bn = fmaxf(0.f, 1.f - tv + a) + fmaxf(0.f, 1.f - tv + bb)
                       + fmaxf(0.f, 1.f - tv + cc);
        hs += hinge_bn * (-lp[n]);
        t0 += expf(tv); s0 += expf(a); s1 += expf(bb); s2 += expf(cc);
    }
    float vals[5] = {hs, t0, s0, s1, s2};
    float outv[5];
    for (int i = 0; i < 5; ++i) {
        red[tid] = vals[i]; __syncthreads();
        for (int s = 128; s > 0; s >>= 1) {
            if (tid < s) red[tid] += red[tid + s];
            __syncthreads();
        }
        outv[i] = red[0]; __syncthreads();
    }
    if (tid == 0) {
        hsum[b] = outv[0];
        accb[b] = (outv[1] >= outv[2] && outv[1] >= outv[3] && outv[1] >= outv[4]) ? 1.0f : 0.0f;
    }
}

__global__ __launch_bounds__(256)
void loss_final_k(const float* __restrict__ hsum, const float* __restrict__ accb,
                  float* __restrict__ out)
{
    __shared__ float red[256];
    const int tid = threadIdx.x;
    float s = 0.f, a = 0.f;
    for (int b = tid; b < NB; b += 256) { s += hsum[b]; a += accb[b]; }
    red[tid] = s; __syncthreads();
    for (int sh = 128; sh > 0; sh >>= 1) { if (tid < sh) red[tid] += red[tid + sh]; __syncthreads(); }
    s = red[0]; __syncthreads();
    red[tid] = a; __syncthreads();
    for (int sh = 128; sh > 0; sh >>= 1) { if (tid < sh) red[tid] += red[tid + sh]; __syncthreads(); }
    a = red[0];
    if (tid == 0) {
        out[0] = s / (float)((size_t)NB * NB);
        out[1] = a / (float)NB;
    }
}

extern "C" void kernel_launch(void* const* d_in, const int* in_sizes, int n_in,
                              void* d_out, int out_size, void* d_ws, size_t ws_size,
                              hipStream_t stream)
{
    const float* target   = (const float*)d_in[0];
    const float* distract = (const float*)d_in[1];
    const float* sWaff = (const float*)d_in[2];
    const float* sbaff = (const float*)d_in[3];
    const float* sWih  = (const float*)d_in[4];
    const float* sWhh  = (const float*)d_in[5];
    const float* sbih  = (const float*)d_in[6];
    const float* sbhh  = (const float*)d_in[7];
    const float* semb  = (const float*)d_in[8];
    const float* sWpr  = (const float*)d_in[9];
    const float* sbpr  = (const float*)d_in[10];
    const float* remb  = (const float*)d_in[11];
    const float* rWih  = (const float*)d_in[12];
    const float* rWhh  = (const float*)d_in[13];
    const float* rbih  = (const float*)d_in[14];
    const float* rbhh  = (const float*)d_in[15];
    const float* rWaff = (const float*)d_in[16];
    const float* rbaff = (const float*)d_in[17];
    const int*   start = (const int*)d_in[18];
    (void)in_sizes; (void)n_in; (void)out_size; (void)ws_size;

    float* out = (float*)d_out;
    float* ws  = (float*)d_ws;

    size_t o = 0;
    float* logits = ws + o; o += (size_t)NB * NV;       // reused as scores[4][NB][NB]
    float* gates  = ws + o; o += (size_t)NB * 4 * NH;   // reused as r_transform
    float* h_s    = ws + o; o += (size_t)NB * NH;
    float* c_s    = ws + o; o += (size_t)NB * NH;
    float* h_r    = ws + o; o += (size_t)NB * NH;
    float* c_r    = ws + o; o += (size_t)NB * NH;
    float* lp     = ws + o; o += NB;
    float* lse    = ws + o; o += NB;
    float* bias_s = ws + o; o += 4 * NH;
    float* bias_r = ws + o; o += 4 * NH;
    float* hsum   = ws + o; o += NB;
    float* accb   = ws + o; o += NB;
    int* msg      = (int*)(ws + o); o += (size_t)NB * NT;
    int* idx0     = (int*)(ws + o); o += NB;
    int* top2i    = (int*)(ws + o); o += 2 * NB;
    __bf16* WHi   = (__bf16*)(ws + o); o += (size_t)NV * NH / 2;
    __bf16* WLo   = (__bf16*)(ws + o); o += (size_t)NV * NH / 2;
    __bf16* hHi   = (__bf16*)(ws + o); o += (size_t)NB * NH / 2;
    __bf16* hLo   = (__bf16*)(ws + o); o += (size_t)NB * NH / 2;
    __bf16* WiHi  = (__bf16*)(ws + o); o += (size_t)(4*NH) * NE / 2;
    __bf16* WiLo  = (__bf16*)(ws + o); o += (size_t)(4*NH) * NE / 2;
    __bf16* WhHi  = (__bf16*)(ws + o); o += (size_t)(4*NH) * NH / 2;
    __bf16* WhLo  = (__bf16*)(ws + o); o += (size_t)(4*NH) * NH / 2;
    __bf16* eHi   = (__bf16*)(ws + o); o += (size_t)NV * NE / 2;
    __bf16* eLo   = (__bf16*)(ws + o); o += (size_t)NV * NE / 2;
    __bf16* hrHi  = (__bf16*)(ws + o); o += (size_t)NB * NH / 2;
    __bf16* hrLo  = (__bf16*)(ws + o); o += (size_t)NB * NH / 2;

    bias_comb_k<<<8, 256, 0, stream>>>(sbih, sbhh, bias_s);
    bias_comb_k<<<8, 256, 0, stream>>>(rbih, rbhh, bias_r);
    init_idx_k<<<4, 256, 0, stream>>>(start, idx0);
    hipMemsetAsync(c_s, 0, (size_t)NB * NH * 4, stream);
    hipMemsetAsync(h_r, 0, (size_t)NB * NH * 4, stream);
    hipMemsetAsync(c_r, 0, (size_t)NB * NH * 4, stream);
    hipMemsetAsync(hrHi, 0, (size_t)NB * NH * 2, stream);
    hipMemsetAsync(hrLo, 0, (size_t)NB * NH * 2, stream);

    // weight/embedding splits (once per launch)
    split_k<<<(NV * NH + 255) / 256, 256, 0, stream>>>(sWpr, WHi, WLo, NV * NH);
    split_k<<<(4*NH*NE + 255) / 256, 256, 0, stream>>>(rWih, WiHi, WiLo, 4*NH*NE);
    split_k<<<(4*NH*NH + 255) / 256, 256, 0, stream>>>(rWhh, WhHi, WhLo, 4*NH*NH);
    split_k<<<(NV * NE + 255) / 256, 256, 0, stream>>>(remb, eHi, eLo, NV * NE);

    // h0 = target @ s_W_aff^T + s_b_aff  (32x128 tile, bit-identical chain)
    h0_gemm<<<dim3(NH/128, NB/32), 256, 0, stream>>>(
        target, sWaff, sbaff, h_s, NB, NH, NF);

    // ---- Sender ----
    const int* cur = idx0;
    for (int t = 0; t < NT; ++t) {
        gemm512<0,1,0,1><<<dim3(4*NH/128, NB/64), 512, 0, stream>>>(
            semb, nullptr, cur, sWih, bias_s, gates, NB, 4*NH, NE);
        gemm512<1,0,0,0><<<dim3(4*NH/128, NB/64), 512, 0, stream>>>(
            h_s, nullptr, nullptr, sWhh, nullptr, gates, NB, 4*NH, NH);
        lstm_cell_k<1><<<NB*NH/256, 256, 0, stream>>>(gates, h_s, c_s, hHi, hLo);
        logits_mfma<<<dim3(NBX, NB / 128), 256, 0, stream>>>(
            hHi, hLo, WHi, WLo, sbpr, logits);
        if (t == NT - 1) {
            argmax2_k<1><<<NB, 256, 0, stream>>>(logits, top2i, lse);
            rescore_k<1><<<NB, 64, 0, stream>>>(h_s, sWpr, sbpr, logits, top2i, lse,
                                                msg + (size_t)t*NB, out + 2, lp, t);
        } else {
            argmax2_k<0><<<NB, 256, 0, stream>>>(logits, top2i, lse);
            rescore_k<0><<<NB, 64, 0, stream>>>(h_s, sWpr, sbpr, logits, top2i, lse,
                                                msg + (size_t)t*NB, out + 2, lp, t);
        }
        cur = msg + (size_t)t * NB;
    }

    // ---- Receiver (split-bf16 MFMA gates; loss path) ----
    for (int t = 0; t < NT; ++t) {
        recv_mfma<<<dim3(4*NH/128, NB/128), 256, 0, stream>>>(
            eHi, eLo, msg + (size_t)t*NB, hrHi, hrLo,
            WiHi, WiLo, WhHi, WhLo, bias_r, gates);
        lstm_cell_k<1><<<NB*NH/256, 256, 0, stream>>>(gates, h_r, c_r, hrHi, hrLo);
    }

    // r_transform = h_r @ r_W_aff^T + r_b_aff
    float* rtr = gates;
    gemm512<0,1,0,0><<<dim3(NF/128, NB/64), 512, 0, stream>>>(
        h_r, nullptr, nullptr, rWaff, rbaff, rtr, NB, NF, NH);

    // scores[z] : z=0 target, z=1..3 distractors (batched via grid.z)
    float* scores = logits;
    gemm512<0,0,1,0><<<dim3(NB/128, NB/64, 1 + ND), 512, 0, stream>>>(
        target, distract, nullptr, rtr, nullptr, scores, NB, NB, NF);

    loss_row_k<<<NB, 256, 0, stream>>>(scores, lp, hsum, accb);
    loss_final_k<<<1, 256, 0, stream>>>(hsum, accb, out);
}